// Round 3
// baseline (9106.257 us; speedup 1.0000x reference)
//
#include <hip/hip_runtime.h>
#include <hip/hip_fp16.h>

typedef _Float16 h2f __attribute__((ext_vector_type(2)));

#define RB 64
#define RT 2048
#define RI 64
#define RH 512
#define C1F 0.9f
#define C2F 0.1f

// K-rows of the extended matvec: 64 u-groups (8 rows each) of W_hidden
// + 8 u-groups of W_in (input projection folded into the recurrence).
#define NU     72
#define NU_REG 48                      // u 0..47  -> pinned in VGPRs (192 regs)
#define NU_LDS 18                      // u 48..65 -> LDS-resident (144 KB)
#define NU_STR (NU - NU_REG - NU_LDS)  // u 66..71 -> streamed from L2 (48 KB/step)
#define THL    (RH + RI)               // extended state vector: [tanh(h); x_t]

static __device__ __forceinline__ h2f bch2(unsigned int v) {
    return __builtin_bit_cast(h2f, v);
}

#if __has_builtin(__builtin_amdgcn_fdot2)
#define DOT2(a, b, c) __builtin_amdgcn_fdot2((a), (b), (c), false)
#else
#define DOT2(a, b, c) fmaf((float)(a).x, (float)(b).x, fmaf((float)(a).y, (float)(b).y, (c)))
#endif

// Pack [W_hidden; W_in] into f16-pair stream P.
// half2 entry e = (u*RH + j)*4 + q holds rows (8u+2q, 8u+2q+1) of column j.
// uint4 entry (u*RH + j) holds rows 8u..8u+7 of column j -> coalesced
// 16B/lane loads in the scan kernel.
__global__ void prep_pack(const float* __restrict__ W, const float* __restrict__ Win,
                          h2f* __restrict__ P) {
    int e = blockIdx.x * 256 + threadIdx.x;
    if (e >= NU * RH * 4) return;
    int q = e & 3;
    int j = (e >> 2) & (RH - 1);
    int u = e >> 11;
    float v0, v1;
    if (u < 64) {                       // W_hidden rows
        int k = 8 * u + 2 * q;
        v0 = W[k * RH + j];
        v1 = W[(k + 1) * RH + j];
    } else {                            // W_in rows
        int i = 8 * (u - 64) + 2 * q;
        v0 = Win[i * RH + j];
        v1 = Win[(i + 1) * RH + j];
    }
    h2f r;
    r.x = (_Float16)v0;
    r.y = (_Float16)v1;
    P[e] = r;
}

// One block per batch element; thread j owns output column j.
// W column: 192 VGPRs (pinned) + 144 KB LDS + 48 KB/step L2 stream.
// State vector [tanh(h); x_t] is f16 in LDS, double-buffered -> one
// barrier per step.
__global__ __launch_bounds__(RH, 2) void rnn_scan(
        const float* __restrict__ x,      // [RB][RT][RI] f32
        const float* __restrict__ sigma,  // [RB][RT][RH] f32
        const float* __restrict__ h0,     // [RB][RH]     f32
        const uint4* __restrict__ P,      // packed f16 [NU*RH] uint4
        float* __restrict__ out)          // [RB][RT][RH] f32, then h_f [RB][RH]
{
    const int b = blockIdx.x;
    const int j = threadIdx.x;

    __shared__ __align__(16) uint4    Wl[NU_LDS * RH];   // 144 KB
    __shared__ __align__(16) _Float16 th[2][THL];        // 2 x 1152 B

    // LDS-resident W segment (cooperative, coalesced)
    for (int e = j; e < NU_LDS * RH; e += RH)
        Wl[e] = P[(size_t)NU_REG * RH + e];

    // VGPR-resident W segment. The opaque asm makes each component the
    // result of an inline-asm op: LLVM cannot rematerialize it, so the
    // values must stay live in registers across the whole t-loop
    // (launch_bounds(512,2) -> 256 VGPR budget; 192 pinned here).
    uint4 wr[NU_REG];
    #pragma unroll
    for (int u = 0; u < NU_REG; ++u)
        wr[u] = P[u * RH + j];
    #pragma unroll
    for (int u = 0; u < NU_REG; ++u)
        asm volatile("" : "+v"(wr[u].x), "+v"(wr[u].y), "+v"(wr[u].z), "+v"(wr[u].w));

    const float* xrow = x + (size_t)b * RT * RI;
    const float* srow = sigma + (size_t)b * RT * RH;
    float*       orow = out + (size_t)b * RT * RH;
    const uint4* Pst  = P + (size_t)(NU_REG + NU_LDS) * RH + j;  // uniform base + j

    float h = h0[b * RH + j];
    {
        float e2 = __expf(2.0f * h);
        th[0][j] = (_Float16)(1.0f - 2.0f / (e2 + 1.0f));
    }
    if (j < RI) th[0][RH + j] = (_Float16)xrow[j];
    __syncthreads();

    for (int t = 0; t < RT; ++t) {
        const uint4* thq = (const uint4*)th[t & 1];
        _Float16*    thw = th[(t & 1) ^ 1];

        // independent loads issued early: this step's sigma, next step's x,
        // and the 6 streamed W groups (L2-hot window, coalesced).
        float sg = srow[(size_t)t * RH + j];
        float xn = 0.0f;
        if (j < RI && t + 1 < RT) xn = xrow[(size_t)(t + 1) * RI + j];
        uint4 ws[NU_STR];
        #pragma unroll
        for (int u = 0; u < NU_STR; ++u) ws[u] = Pst[u * RH];

        // 4 independent accumulator chains
        float a0 = 0.f, a1 = 0.f, a2 = 0.f, a3 = 0.f;

        #pragma unroll
        for (int u = 0; u < NU_REG; ++u) {
            uint4 tv = thq[u];            // uniform address -> LDS broadcast
            uint4 wv = wr[u];
            a0 = DOT2(bch2(wv.x), bch2(tv.x), a0);
            a1 = DOT2(bch2(wv.y), bch2(tv.y), a1);
            a2 = DOT2(bch2(wv.z), bch2(tv.z), a2);
            a3 = DOT2(bch2(wv.w), bch2(tv.w), a3);
        }
        #pragma unroll
        for (int u = 0; u < NU_LDS; ++u) {
            uint4 tv = thq[NU_REG + u];
            uint4 wv = Wl[u * RH + j];    // consecutive lanes -> conflict-free
            a0 = DOT2(bch2(wv.x), bch2(tv.x), a0);
            a1 = DOT2(bch2(wv.y), bch2(tv.y), a1);
            a2 = DOT2(bch2(wv.z), bch2(tv.z), a2);
            a3 = DOT2(bch2(wv.w), bch2(tv.w), a3);
        }
        #pragma unroll
        for (int u = 0; u < NU_STR; ++u) {
            uint4 tv = thq[NU_REG + NU_LDS + u];
            uint4 wv = ws[u];
            a0 = DOT2(bch2(wv.x), bch2(tv.x), a0);
            a1 = DOT2(bch2(wv.y), bch2(tv.y), a1);
            a2 = DOT2(bch2(wv.z), bch2(tv.z), a2);
            a3 = DOT2(bch2(wv.w), bch2(tv.w), a3);
        }

        float hn = C1F * h + C2F * ((a0 + a1) + (a2 + a3)) + sg;
        orow[(size_t)t * RH + j] = hn;
        h = hn;

        float e2 = __expf(2.0f * hn);
        thw[j] = (_Float16)(1.0f - 2.0f / (e2 + 1.0f));
        if (j < RI && t + 1 < RT) thw[RH + j] = (_Float16)xn;
        __syncthreads();
    }

    out[(size_t)RB * RT * RH + (size_t)b * RH + j] = h;
}

extern "C" void kernel_launch(void* const* d_in, const int* in_sizes, int n_in,
                              void* d_out, int out_size, void* d_ws, size_t ws_size,
                              hipStream_t stream) {
    const float* x   = (const float*)d_in[0];
    const float* Win = (const float*)d_in[1];
    const float* Wh  = (const float*)d_in[2];
    const float* sg  = (const float*)d_in[3];
    const float* h0  = (const float*)d_in[4];
    float* out = (float*)d_out;

    h2f* P = (h2f*)d_ws;   // 576 KB packed [W_hidden; W_in] in f16 pairs

    const int n_entries = NU * RH * 4;
    hipLaunchKernelGGL(prep_pack, dim3((n_entries + 255) / 256), dim3(256), 0, stream,
                       Wh, Win, P);
    hipLaunchKernelGGL(rnn_scan, dim3(RB), dim3(RH), 0, stream,
                       x, sg, h0, (const uint4*)d_ws, out);
}